// Round 17
// baseline (1857.357 us; speedup 1.0000x reference)
//
#include <hip/hip_runtime.h>
#include <hip/hip_bf16.h>
#include <cstddef>

// Problem constants
constexpr int B = 128;
constexpr int T = 500;
constexpr int C = 128;     // n_maps
constexpr int CIN = 80;    // n_mels
constexpr int NL = 35;     // labels
constexpr size_t NBCT = (size_t)B * C * T;  // 8,192,000 floats
constexpr int WPAD = 132;                   // LDS i-stride (conflict-free)
constexpr int I0 = 96;                      // conv0 padded input channels
constexpr int IPAD0 = 104;                  // conv0 LDS i-stride
constexpr int NT = 64;                      // conv t-tile
constexpr int NPART = 1024;                 // partial-stats rows

typedef __attribute__((ext_vector_type(8))) _Float16 half8;  // 8 fp16 = 4 VGPR
typedef __attribute__((ext_vector_type(4))) _Float16 half4;
typedef __attribute__((ext_vector_type(4))) float f32x4;

// Static device scratch. Activations in [b][t][c] layout.
__device__ float g_zA[NBCT];         // RK4 state ping (fp32)
__device__ float g_zB[NBCT];         // RK4 state pong (fp32)
__device__ _Float16 g_z16[NBCT];     // fp16 snapshot of current z (refreshed at fin)
__device__ _Float16 g_accA[NBCT];    // RK4 k-accumulator ping (fp16)
__device__ _Float16 g_accB[NBCT];    // RK4 k-accumulator pong (fp16)
__device__ _Float16 g_t1[NBCT];      // conv1 out (fp16, pre-BN)
__device__ _Float16 g_t2[NBCT];      // conv2 out (fp16, pre-BN)
__device__ _Float16 g_t3[NBCT];      // conv3 out (fp16, pre-BN)
// Per-block partial stats, TRANSPOSED layout [p][c]: block stores are 512B
// contiguous (R16 ERRATA: [c][p] layout cost 30MB/dispatch write amp —
// 128 lanes x 4 arrays x 64B-line per 4B payload).
__device__ float g_ps1[NPART * C], g_pq1[NPART * C];
__device__ float g_ps2[NPART * C], g_pq2[NPART * C];
__device__ float g_ps3[NPART * C], g_pq3[NPART * C];
__device__ float g_m1[C], g_r1[C], g_m2[C], g_r2[C], g_m3[C], g_r3[C];
__device__ float g_featp[B * 4 * C];              // head partial sums
// conv0 weights, layout [kw][o][i] (i-stride I0), fp16
__device__ _Float16 g_w0f[3 * C * I0];
// main conv weights, MFMA-native layout [kw][kseg=i>>3][o][j=i&7], fp16
__device__ _Float16 g_w1f[9 * C * C];
__device__ _Float16 g_w2f[9 * C * C];
__device__ _Float16 g_w3f[1 * C * C];

__device__ inline half8 h8zero() {
  half8 v;
#pragma unroll
  for (int j = 0; j < 8; j++) v[j] = (_Float16)0.f;
  return v;
}

// XCD-aware swizzle of the 1024-block conv grid (8 tiles x 128 b).
__device__ inline void swz_block(int& tile, int& b) {
  int flat = blockIdx.y * 8 + blockIdx.x;
  int swz = (flat & 7) * 128 + (flat >> 3);
  tile = swz & 7;
  b = swz >> 3;
}

// ---------------------------------------------------------------------------
// Weight prep: w [O][I][KW] fp32 -> fp16, layout [kw][i>>3][o][i&7]
// ---------------------------------------------------------------------------
template <int KW>
__global__ __launch_bounds__(256) void prep_weights_f16(
    const float* __restrict__ w, _Float16* __restrict__ wf) {
  int idx = blockIdx.x * 256 + threadIdx.x;
  if (idx >= C * C * KW) return;
  int kw = idx % KW;
  int i = (idx / KW) % C;
  int o = idx / (KW * C);
  size_t dst = (((size_t)kw * 16 + (i >> 3)) * C + o) * 8 + (i & 7);
  wf[dst] = (_Float16)w[idx];
}

// conv0 weights: w0 [O=128][I=80][3] -> [3][O][I0=96] fp16 (zero-padded i>=80)
__global__ __launch_bounds__(256) void prep_w0_f16(
    const float* __restrict__ w, _Float16* __restrict__ wf) {
  int idx = blockIdx.x * 256 + threadIdx.x;
  if (idx >= 3 * C * I0) return;
  int i = idx % I0;
  int o = (idx / I0) % C;
  int kw = idx / (I0 * C);
  float v = 0.f;
  if (i < CIN) v = w[((size_t)o * CIN + i) * 3 + kw];
  wf[((size_t)kw * C + o) * I0 + i] = (_Float16)v;
}

// ---------------------------------------------------------------------------
// Reduce partials -> mean, rstd per channel. [p][c] layout: grid
// (8 channel-groups, ntensors), 256 thr = 16 p-rows x 16 channels; every
// 64B line is fully consumed (no read amplification).
// ---------------------------------------------------------------------------
__device__ inline void reduce_oneT(const float* __restrict__ ps,
                                   const float* __restrict__ pq,
                                   float* __restrict__ om,
                                   float* __restrict__ orr, int cg) {
  const int cl = threadIdx.x & 15;
  const int pr = threadIdx.x >> 4;  // 0..15
  const int c = cg * 16 + cl;
  float s = 0.f, q = 0.f;
  for (int p = pr; p < NPART; p += 16) {
    s += ps[(size_t)p * C + c];
    q += pq[(size_t)p * C + c];
  }
  __shared__ float lss[16][17], lsq[16][17];
  lss[pr][cl] = s;
  lsq[pr][cl] = q;
  __syncthreads();
  if (threadIdx.x < 16) {
    float S = 0.f, Q = 0.f;
#pragma unroll
    for (int r = 0; r < 16; r++) {
      S += lss[r][threadIdx.x];
      Q += lsq[r][threadIdx.x];
    }
    const float invn = 1.f / 64000.f;
    float m = S * invn;
    float v = Q * invn - m * m;
    om[cg * 16 + threadIdx.x] = m;
    orr[cg * 16 + threadIdx.x] = rsqrtf(v + 1e-5f);
  }
}

__global__ __launch_bounds__(256) void reduce_stats(
    const float* __restrict__ ps, const float* __restrict__ pq,
    float* __restrict__ om, float* __restrict__ orr) {
  reduce_oneT(ps, pq, om, orr, blockIdx.x);
}

__global__ __launch_bounds__(256) void reduce_stats2(
    const float* __restrict__ psA, const float* __restrict__ pqA,
    float* __restrict__ omA, float* __restrict__ orA,
    const float* __restrict__ psB, const float* __restrict__ pqB,
    float* __restrict__ omB, float* __restrict__ orB) {
  if (blockIdx.y == 0)
    reduce_oneT(psA, pqA, omA, orA, blockIdx.x);
  else
    reduce_oneT(psB, pqB, omB, orB, blockIdx.x);
}

// ---------------------------------------------------------------------------
// Epilogues (R13 direct-store path — R16's LDS-transpose epilogue measured
// byte-neutral: fragment stores already write-combine across waves).
// D layout (16x16x32): col(t)=lane&15, row(o)=quad*4+reg.
// ---------------------------------------------------------------------------
template <int NG, int NTG>
__device__ inline void store_and_stats_f(f32x4 (&dacc)[NG][NTG],
                                         float* __restrict__ outb,
                                         float* __restrict__ ssum,
                                         float* __restrict__ ssq, int tbase,
                                         int og0, int quad, int m15) {
#pragma unroll
  for (int g = 0; g < NG; g++) {
    float rs[4] = {0.f, 0.f, 0.f, 0.f}, rq[4] = {0.f, 0.f, 0.f, 0.f};
#pragma unroll
    for (int tg = 0; tg < NTG; tg++) {
      int t = tbase + tg * 16 + m15;
      bool valid = t < T;
      f32x4 d = dacc[g][tg];
      if (valid)
        *(f32x4*)(outb + (size_t)t * C + (og0 + g) * 16 + quad * 4) = d;
#pragma unroll
      for (int r = 0; r < 4; r++) {
        float v = valid ? d[r] : 0.f;
        rs[r] += v;
        rq[r] += v * v;
      }
    }
#pragma unroll
    for (int sh = 1; sh < 16; sh <<= 1) {
#pragma unroll
      for (int r = 0; r < 4; r++) {
        rs[r] += __shfl_xor(rs[r], sh);
        rq[r] += __shfl_xor(rq[r], sh);
      }
    }
    if (m15 == 0) {
      int o = (og0 + g) * 16 + quad * 4;
#pragma unroll
      for (int r = 0; r < 4; r++) {
        atomicAdd(&ssum[o + r], rs[r]);
        atomicAdd(&ssq[o + r], rq[r]);
      }
    }
  }
}

template <int NG, int NTG>
__device__ inline void store_and_stats_h(f32x4 (&dacc)[NG][NTG],
                                         _Float16* __restrict__ outb,
                                         float* __restrict__ ssum,
                                         float* __restrict__ ssq, int tbase,
                                         int og0, int quad, int m15) {
#pragma unroll
  for (int g = 0; g < NG; g++) {
    float rs[4] = {0.f, 0.f, 0.f, 0.f}, rq[4] = {0.f, 0.f, 0.f, 0.f};
#pragma unroll
    for (int tg = 0; tg < NTG; tg++) {
      int t = tbase + tg * 16 + m15;
      bool valid = t < T;
      f32x4 d = dacc[g][tg];
      if (valid) {
        half4 h;
#pragma unroll
        for (int r = 0; r < 4; r++) h[r] = (_Float16)d[r];
        *(half4*)(outb + (size_t)t * C + (og0 + g) * 16 + quad * 4) = h;
      }
#pragma unroll
      for (int r = 0; r < 4; r++) {
        float v = valid ? d[r] : 0.f;
        rs[r] += v;
        rq[r] += v * v;
      }
    }
#pragma unroll
    for (int sh = 1; sh < 16; sh <<= 1) {
#pragma unroll
      for (int r = 0; r < 4; r++) {
        rs[r] += __shfl_xor(rs[r], sh);
        rq[r] += __shfl_xor(rq[r], sh);
      }
    }
    if (m15 == 0) {
      int o = (og0 + g) * 16 + quad * 4;
#pragma unroll
      for (int r = 0; r < 4; r++) {
        atomicAdd(&ssum[o + r], rs[r]);
        atomicAdd(&ssq[o + r], rq[r]);
      }
    }
  }
}

// ---------------------------------------------------------------------------
// conv13f: fused combine(i-1) + conv1 (KW=9) + conv3 (KW=1). R13 structure
// (256 thr, og0=wv*2, NTG=4, z16 snapshot, XCD swizzle, ping-pong buffers,
// direct fragment stores). Stats stored to [p][c] layout (512B contiguous).
// ---------------------------------------------------------------------------
__global__ __launch_bounds__(256, 4) void conv13f(
    const _Float16* __restrict__ t2g, const _Float16* __restrict__ t3g,
    const float* __restrict__ m2, const float* __restrict__ r2,
    const float* __restrict__ m3, const float* __restrict__ r3,
    const float* __restrict__ zc, _Float16* __restrict__ z16,
    const _Float16* __restrict__ accr, float* __restrict__ zn,
    _Float16* __restrict__ accw, const _Float16* __restrict__ w9,
    const _Float16* __restrict__ w1, _Float16* __restrict__ out1,
    _Float16* __restrict__ out3, float* __restrict__ ps1,
    float* __restrict__ pq1, float* __restrict__ ps3,
    float* __restrict__ pq3, float wacc, float anext, int mode, int initf,
    int finf) {
  constexpr int PAD = 4;
  constexpr int ROWS = NT + 8;  // 72
  __shared__ __align__(16) _Float16 sh[ROWS * WPAD];
  __shared__ float ssum1[C], ssq1[C], ssum3[C], ssq3[C];
  __shared__ float sm2[C], sr2[C], sm3[C], sr3[C];

  const int tid = threadIdx.x;
  int tile, b;
  swz_block(tile, b);
  const int t0 = tile * NT;

  if (tid < 128) {
    ssum1[tid] = 0.f; ssq1[tid] = 0.f;
    ssum3[tid] = 0.f; ssq3[tid] = 0.f;
    if (mode) {
      sm2[tid] = m2[tid]; sr2[tid] = r2[tid];
      sm3[tid] = m3[tid]; sr3[tid] = r3[tid];
    }
  }
  __syncthreads();  // BN params ready before staging uses them

  for (int e = tid; e < ROWS * 16; e += 256) {
    int r = e >> 4;
    int c8 = e & 15;
    int t = t0 - PAD + r;
    half8 v = h8zero();
    if (t >= 0 && t < T) {
      size_t off = (size_t)b * T * C + (size_t)t * C + c8 * 8;
      if (mode == 0) {
        v = *(const half8*)(z16 + off);
      } else {
        half8 h2 = *(const half8*)(t2g + off);
        half8 h3 = *(const half8*)(t3g + off);
        float zf[8];
        if (finf) {
          float4 z0 = *(const float4*)(zc + off);
          float4 z1 = *(const float4*)(zc + off + 4);
          zf[0] = z0.x; zf[1] = z0.y; zf[2] = z0.z; zf[3] = z0.w;
          zf[4] = z1.x; zf[5] = z1.y; zf[6] = z1.z; zf[7] = z1.w;
        } else {
          half8 hz = *(const half8*)(z16 + off);
#pragma unroll
          for (int j = 0; j < 8; j++) zf[j] = (float)hz[j];
        }
        half8 ha = h8zero();
        if (!initf) ha = *(const half8*)(accr + off);
        int c = c8 * 8;
        float va[8], zo[8];
#pragma unroll
        for (int j = 0; j < 8; j++) {
          float f2 = (float)h2[j];
          float f3 = (float)h3[j];
          float k = fmaxf((f2 - sm2[c + j]) * sr2[c + j] +
                              fmaxf((f3 - sm3[c + j]) * sr3[c + j], 0.f),
                          0.f);
          va[j] = initf ? wacc * k : (float)ha[j] + wacc * k;
          zo[j] = zf[j] + anext * (finf ? va[j] : k);
          v[j] = (_Float16)zo[j];
        }
        bool owned = (r >= PAD) && (r < PAD + NT);
        if (owned) {
          if (finf) {
            *(float4*)(zn + off) = make_float4(zo[0], zo[1], zo[2], zo[3]);
            *(float4*)(zn + off + 4) = make_float4(zo[4], zo[5], zo[6], zo[7]);
            *(half8*)(z16 + off) = v;  // refresh fp16 snapshot of new z
          } else {
            half8 aw;
#pragma unroll
            for (int j = 0; j < 8; j++) aw[j] = (_Float16)va[j];
            *(half8*)(accw + off) = aw;
          }
        }
      }
    }
    *(half8*)&sh[r * WPAD + c8 * 8] = v;
  }
  __syncthreads();

  const int wv = tid >> 6;
  const int lane = tid & 63;
  const int quad = lane >> 4;
  const int m15 = lane & 15;
  const int og0 = wv * 2;  // waves own disjoint o-pairs: no A duplication

  const half8* __restrict__ A9 = (const half8*)w9;
  const half8* __restrict__ A1 = (const half8*)w1;

  // --- conv3 (KW=1): 4 rounds, retire accumulator early ---
  {
    f32x4 d3[2][4];
#pragma unroll
    for (int g = 0; g < 2; g++)
#pragma unroll
      for (int tg = 0; tg < 4; tg++) d3[g][tg] = f32x4{0.f, 0.f, 0.f, 0.f};
#pragma unroll
    for (int ic = 0; ic < 4; ic++) {
      const int kof = ic * 32 + quad * 8;
      half8 af[2];
#pragma unroll
      for (int g = 0; g < 2; g++)
        af[g] = A1[(ic * 4 + quad) * C + (og0 + g) * 16 + m15];
      half8 bf[4];
#pragma unroll
      for (int tg = 0; tg < 4; tg++)
        bf[tg] = *(const half8*)(sh + (tg * 16 + m15 + PAD) * WPAD + kof);
#pragma unroll
      for (int g = 0; g < 2; g++)
#pragma unroll
        for (int tg = 0; tg < 4; tg++)
          d3[g][tg] = __builtin_amdgcn_mfma_f32_16x16x32_f16(
              af[g], bf[tg], d3[g][tg], 0, 0, 0);
    }
    _Float16* __restrict__ o3b = out3 + (size_t)b * T * C;
    store_and_stats_h<2, 4>(d3, o3b, ssum3, ssq3, t0, og0, quad, m15);
  }

  // --- conv1 (KW=9): 36 rounds ---
  f32x4 d1[2][4];
#pragma unroll
  for (int g = 0; g < 2; g++)
#pragma unroll
    for (int tg = 0; tg < 4; tg++) d1[g][tg] = f32x4{0.f, 0.f, 0.f, 0.f};

  for (int kw = 0; kw < 9; kw++) {
#pragma unroll
    for (int ic = 0; ic < 4; ic++) {
      const int kof = ic * 32 + quad * 8;
      half8 af[2];
#pragma unroll
      for (int g = 0; g < 2; g++)
        af[g] = A9[(kw * 16 + ic * 4 + quad) * C + (og0 + g) * 16 + m15];
      half8 bf[4];
#pragma unroll
      for (int tg = 0; tg < 4; tg++)
        bf[tg] = *(const half8*)(sh + (tg * 16 + m15 + kw) * WPAD + kof);
#pragma unroll
      for (int g = 0; g < 2; g++)
#pragma unroll
        for (int tg = 0; tg < 4; tg++)
          d1[g][tg] = __builtin_amdgcn_mfma_f32_16x16x32_f16(
              af[g], bf[tg], d1[g][tg], 0, 0, 0);
    }
  }

  _Float16* __restrict__ o1b = out1 + (size_t)b * T * C;
  store_and_stats_h<2, 4>(d1, o1b, ssum1, ssq1, t0, og0, quad, m15);
  __syncthreads();
  int p = b * 8 + tile;
  if (tid < 128) {
    ps1[(size_t)p * C + tid] = ssum1[tid];
    pq1[(size_t)p * C + tid] = ssq1[tid];
    ps3[(size_t)p * C + tid] = ssum3[tid];
    pq3[(size_t)p * C + tid] = ssq3[tid];
  }
}

// ---------------------------------------------------------------------------
// conv2 (KW=9, PAD=4): BN+relu on staging from precomputed mean/rstd;
// minimal-A geometry + XCD swizzle; [p][c] stats store.
// ---------------------------------------------------------------------------
__global__ __launch_bounds__(256, 4) void conv2_bn(
    const _Float16* __restrict__ in, const _Float16* __restrict__ wf,
    const float* __restrict__ bnm, const float* __restrict__ bnr,
    _Float16* __restrict__ out, float* __restrict__ ps,
    float* __restrict__ pq) {
  constexpr int KW = 9, PAD = 4;
  constexpr int ROWS = NT + KW - 1;  // 72
  __shared__ __align__(16) _Float16 sh[ROWS * WPAD];
  __shared__ float ssum[C], ssq[C];
  __shared__ float sbm[C], sbr[C];

  const int tid = threadIdx.x;
  int tile, b;
  swz_block(tile, b);
  const int t0 = tile * NT;

  if (tid < 128) {
    sbm[tid] = bnm[tid];
    sbr[tid] = bnr[tid];
    ssum[tid] = 0.f;
    ssq[tid] = 0.f;
  }
  __syncthreads();  // BN params ready before staging uses them

  const _Float16* __restrict__ inb = in + (size_t)b * T * C;
  for (int e = tid; e < ROWS * 16; e += 256) {
    int r = e >> 4;
    int c8 = e & 15;
    int t = t0 - PAD + r;
    half8 v = h8zero();
    if (t >= 0 && t < T) {
      half8 u = *(const half8*)(inb + (size_t)t * C + c8 * 8);
      int c = c8 * 8;
#pragma unroll
      for (int j = 0; j < 8; j++) {
        float f = (float)u[j];
        f = fmaxf((f - sbm[c + j]) * sbr[c + j], 0.f);
        v[j] = (_Float16)f;
      }
    }
    *(half8*)&sh[r * WPAD + c8 * 8] = v;
  }
  __syncthreads();

  const int wv = tid >> 6;
  const int lane = tid & 63;
  const int quad = lane >> 4;
  const int m15 = lane & 15;
  const int og0 = wv * 2;

  const half8* __restrict__ Af = (const half8*)wf;

  f32x4 dacc[2][4];
#pragma unroll
  for (int g = 0; g < 2; g++)
#pragma unroll
    for (int tg = 0; tg < 4; tg++) dacc[g][tg] = f32x4{0.f, 0.f, 0.f, 0.f};

  for (int kw = 0; kw < 9; kw++) {
#pragma unroll
    for (int ic = 0; ic < 4; ic++) {
      const int kof = ic * 32 + quad * 8;
      half8 af[2];
#pragma unroll
      for (int g = 0; g < 2; g++)
        af[g] = Af[(kw * 16 + ic * 4 + quad) * C + (og0 + g) * 16 + m15];
      half8 bf[4];
#pragma unroll
      for (int tg = 0; tg < 4; tg++)
        bf[tg] = *(const half8*)(sh + (tg * 16 + m15 + kw) * WPAD + kof);
#pragma unroll
      for (int g = 0; g < 2; g++)
#pragma unroll
        for (int tg = 0; tg < 4; tg++)
          dacc[g][tg] = __builtin_amdgcn_mfma_f32_16x16x32_f16(
              af[g], bf[tg], dacc[g][tg], 0, 0, 0);
    }
  }

  _Float16* __restrict__ outb = out + (size_t)b * T * C;
  store_and_stats_h<2, 4>(dacc, outb, ssum, ssq, t0, og0, quad, m15);
  __syncthreads();
  int p = b * 8 + tile;
  if (tid < 128) {
    ps[(size_t)p * C + tid] = ssum[tid];
    pq[(size_t)p * C + tid] = ssq[tid];
  }
}

// ---------------------------------------------------------------------------
// conv0: single fp16 16x16x32 MFMA. Output z fp32; [p][c] stats store.
// ---------------------------------------------------------------------------
__global__ __launch_bounds__(256) void conv0_mfma(
    const float* __restrict__ in, const _Float16* __restrict__ wf,
    float* __restrict__ out, float* __restrict__ ps, float* __restrict__ pq) {
  constexpr int KW = 3, PAD = 1;
  constexpr int ROWS = NT + KW - 1;  // 66
  __shared__ __align__(16) _Float16 sh[ROWS * IPAD0];
  __shared__ float ssum[C], ssq[C];

  const int tid = threadIdx.x;
  const int tile = blockIdx.x;
  const int b = blockIdx.y;
  const int t0 = tile * NT;

  if (tid < 128) { ssum[tid] = 0.f; ssq[tid] = 0.f; }
  __syncthreads();

  const float* __restrict__ inb = in + (size_t)b * CIN * T;
  for (int e = tid; e < I0 * ROWS; e += 256) {
    int i = e / ROWS;
    int r = e % ROWS;
    int t = t0 - PAD + r;
    float v = 0.f;
    if (i < CIN && t >= 0 && t < T) v = inb[(size_t)i * T + t];
    sh[r * IPAD0 + i] = (_Float16)v;
  }
  __syncthreads();

  const int wv = tid >> 6;
  const int lane = tid & 63;
  const int quad = lane >> 4;
  const int m15 = lane & 15;
  const int og0 = wv * 2;

  f32x4 dacc[2][4];
#pragma unroll
  for (int g = 0; g < 2; g++)
#pragma unroll
    for (int tg = 0; tg < 4; tg++) dacc[g][tg] = f32x4{0.f, 0.f, 0.f, 0.f};

  for (int kw = 0; kw < KW; kw++) {
    const _Float16* __restrict__ wk = wf + (size_t)kw * C * I0;
#pragma unroll
    for (int ic = 0; ic < 3; ic++) {
      const int kof = ic * 32 + quad * 8;
      half8 af[2];
#pragma unroll
      for (int g = 0; g < 2; g++) {
        size_t off = (size_t)((og0 + g) * 16 + m15) * I0 + kof;
        af[g] = *(const half8*)(wk + off);
      }
      half8 bf[4];
#pragma unroll
      for (int tg = 0; tg < 4; tg++) {
        int off = (tg * 16 + m15 + kw) * IPAD0 + kof;
        bf[tg] = *(const half8*)(sh + off);
      }
#pragma unroll
      for (int g = 0; g < 2; g++)
#pragma unroll
        for (int tg = 0; tg < 4; tg++)
          dacc[g][tg] = __builtin_amdgcn_mfma_f32_16x16x32_f16(
              af[g], bf[tg], dacc[g][tg], 0, 0, 0);
    }
  }

  float* __restrict__ outb = out + (size_t)b * T * C;
  store_and_stats_f<2, 4>(dacc, outb, ssum, ssq, t0, og0, quad, m15);
  __syncthreads();
  int p = b * 8 + tile;
  if (tid < 128) {
    ps[(size_t)p * C + tid] = ssum[tid];
    pq[(size_t)p * C + tid] = ssq[tid];
  }
}

// ---------------------------------------------------------------------------
// z = relu((z - m[c]) * r[c]) in place (fp32) + fp16 snapshot z16.
// ---------------------------------------------------------------------------
__global__ __launch_bounds__(256) void apply_bn_relu(
    float* __restrict__ x, const float* __restrict__ m,
    const float* __restrict__ r, _Float16* __restrict__ zh) {
  __shared__ float sm[C], sr[C];
  if (threadIdx.x < 128) {
    sm[threadIdx.x] = m[threadIdx.x];
    sr[threadIdx.x] = r[threadIdx.x];
  }
  __syncthreads();
  const size_t total4 = NBCT / 4;
  size_t stride = (size_t)gridDim.x * 256;
  for (size_t i4 = (size_t)blockIdx.x * 256 + threadIdx.x; i4 < total4;
       i4 += stride) {
    int c = (int)((i4 & 31) * 4);
    float4 v = ((float4*)x)[i4];
    v.x = fmaxf((v.x - sm[c]) * sr[c], 0.f);
    v.y = fmaxf((v.y - sm[c + 1]) * sr[c + 1], 0.f);
    v.z = fmaxf((v.z - sm[c + 2]) * sr[c + 2], 0.f);
    v.w = fmaxf((v.w - sm[c + 3]) * sr[c + 3], 0.f);
    ((float4*)x)[i4] = v;
    half4 h;
    h[0] = (_Float16)v.x;
    h[1] = (_Float16)v.y;
    h[2] = (_Float16)v.z;
    h[3] = (_Float16)v.w;
    *(half4*)(zh + i4 * 4) = h;
  }
}

// ---------------------------------------------------------------------------
// feat_fin: fused final combine + pooling. z_final = z + anext*(acc+wacc*k)
// computed on the fly (never materialized); partial t-sums into featp.
// grid (B, 4), 256 thr (2 t-phases x 128 channels).
// ---------------------------------------------------------------------------
__global__ __launch_bounds__(256) void feat_fin(
    const _Float16* __restrict__ t2, const _Float16* __restrict__ t3,
    const float* __restrict__ m2, const float* __restrict__ r2,
    const float* __restrict__ m3, const float* __restrict__ r3,
    const float* __restrict__ z, const _Float16* __restrict__ acc,
    float wacc, float anext, float* __restrict__ fp) {
  __shared__ float sm2[C], sr2[C], sm3[C], sr3[C];
  if (threadIdx.x < 128) {
    sm2[threadIdx.x] = m2[threadIdx.x];
    sr2[threadIdx.x] = r2[threadIdx.x];
    sm3[threadIdx.x] = m3[threadIdx.x];
    sr3[threadIdx.x] = r3[threadIdx.x];
  }
  __syncthreads();
  const int b = blockIdx.x;
  const int s = blockIdx.y;
  const int c = threadIdx.x & 127;
  const int h = threadIdx.x >> 7;
  float sum = 0.f;
  for (int t = s * 125 + h; t < (s + 1) * 125; t += 2) {
    size_t off = (size_t)b * T * C + (size_t)t * C + c;
    float f2 = (float)t2[off];
    float f3 = (float)t3[off];
    float k = fmaxf((f2 - sm2[c]) * sr2[c] +
                        fmaxf((f3 - sm3[c]) * sr3[c], 0.f),
                    0.f);
    float va = (float)acc[off] + wacc * k;
    sum += z[off] + anext * va;
  }
  __shared__ float sf[2][C];
  sf[h][c] = sum;
  __syncthreads();
  if (threadIdx.x < 128)
    fp[((size_t)b * 4 + s) * C + threadIdx.x] =
        sf[0][threadIdx.x] + sf[1][threadIdx.x];
}

// head, phase 2: feat = sum(partials)/500; out = feat @ ow^T + ob.
__global__ __launch_bounds__(256) void head2(
    const float* __restrict__ fp, const float* __restrict__ ow,
    const float* __restrict__ ob, float* __restrict__ out) {
  const int b = blockIdx.x;
  __shared__ float feat[C];
  if (threadIdx.x < 128) {
    float s = 0.f;
#pragma unroll
    for (int p = 0; p < 4; p++) s += fp[((size_t)b * 4 + p) * C + threadIdx.x];
    feat[threadIdx.x] = s * (1.f / 500.f);
  }
  __syncthreads();
  if (threadIdx.x < NL) {
    int l = threadIdx.x;
    float o = ob[l];
    for (int j = 0; j < C; j++) o = fmaf(feat[j], ow[l * C + j], o);
    out[b * NL + l] = o;
  }
}

// ---------------------------------------------------------------------------
extern "C" void kernel_launch(void* const* d_in, const int* in_sizes, int n_in,
                              void* d_out, int out_size, void* d_ws,
                              size_t ws_size, hipStream_t stream) {
  const float* x  = (const float*)d_in[0];
  const float* w0 = (const float*)d_in[1];
  const float* w1 = (const float*)d_in[2];
  const float* w2 = (const float*)d_in[3];
  const float* w3 = (const float*)d_in[4];
  const float* ow = (const float*)d_in[5];
  const float* ob = (const float*)d_in[6];
  float* out = (float*)d_out;

  static float *zA, *zB, *featp;
  static float *ps1, *pq1, *ps2, *pq2, *ps3, *pq3;
  static float *m1, *r1, *m2, *r2, *m3, *r3;
  static _Float16 *z16, *accA, *accB, *t1, *t2, *t3;
  static _Float16 *w0f, *w1f, *w2f, *w3f;
  static bool inited = false;
  if (!inited) {
    void* p;
#define GET(sym, var) hipGetSymbolAddress(&p, HIP_SYMBOL(sym)); var = (decltype(var))p;
    GET(g_zA, zA) GET(g_zB, zB) GET(g_z16, z16)
    GET(g_accA, accA) GET(g_accB, accB)
    GET(g_t1, t1) GET(g_t2, t2) GET(g_t3, t3)
    GET(g_ps1, ps1) GET(g_pq1, pq1) GET(g_ps2, ps2) GET(g_pq2, pq2)
    GET(g_ps3, ps3) GET(g_pq3, pq3)
    GET(g_m1, m1) GET(g_r1, r1) GET(g_m2, m2) GET(g_r2, r2)
    GET(g_m3, m3) GET(g_r3, r3) GET(g_featp, featp)
    GET(g_w0f, w0f) GET(g_w1f, w1f) GET(g_w2f, w2f) GET(g_w3f, w3f)
#undef GET
    inited = true;
  }

  // Weight prep (cheap, every launch)
  prep_w0_f16<<<(3 * C * I0 + 255) / 256, 256, 0, stream>>>(w0, w0f);
  prep_weights_f16<9><<<(C * C * 9 + 255) / 256, 256, 0, stream>>>(w1, w1f);
  prep_weights_f16<9><<<(C * C * 9 + 255) / 256, 256, 0, stream>>>(w2, w2f);
  prep_weights_f16<1><<<(C * C * 1 + 255) / 256, 256, 0, stream>>>(w3, w3f);

  const dim3 convGrid(8, B);   // NT=64 tiles -> 1024 blocks of 256 thr
  const int ewGrid = 1024;
  const float dt = 0.25f;

  // conv0 -> reduce -> bn+relu (into zA fp32 + z16 fp16).
  conv0_mfma<<<dim3(8, B), 256, 0, stream>>>(x, w0f, zA, ps1, pq1);
  reduce_stats<<<dim3(8), 256, 0, stream>>>(ps1, pq1, m1, r1);
  apply_bn_relu<<<ewGrid, 256, 0, stream>>>(zA, m1, r1, z16);

  const float waccs[4] = {1.f, 2.f, 2.f, 1.f};
  const float anexts[4] = {0.5f * dt, 0.5f * dt, dt, dt / 6.f};

  float* zcur = zA;
  float* znext = zB;
  _Float16* accbuf[2] = {accA, accB};
  int flip = 0;

  for (int i = 0; i < 16; i++) {
    int sp = (i + 3) % 4;  // previous iteration's s (valid for i>=1)
    int mode = (i == 0) ? 0 : 1;
    int initf = (sp == 0) ? 1 : 0;
    int finf = (sp == 3) ? 1 : 0;
    conv13f<<<convGrid, 256, 0, stream>>>(
        t2, t3, m2, r2, m3, r3, zcur, z16, accbuf[flip], znext,
        accbuf[flip ^ 1], w1f, w3f, t1, t3, ps1, pq1, ps3, pq3,
        mode ? waccs[sp] : 0.f, mode ? anexts[sp] : 0.f, mode, initf, finf);
    if (i >= 1) {
      if (!finf) {
        flip ^= 1;                       // acc written into flip^1
      } else {
        float* tmp = zcur; zcur = znext; znext = tmp;  // fin wrote z
      }
    }
    reduce_stats2<<<dim3(8, 2), 256, 0, stream>>>(
        ps1, pq1, m1, r1, ps3, pq3, m3, r3);
    conv2_bn<<<convGrid, 256, 0, stream>>>(
        t1, w2f, m1, r1, t2, ps2, pq2);
    reduce_stats<<<dim3(8), 256, 0, stream>>>(ps2, pq2, m2, r2);
  }

  // Fused final combine + pooling (z_final never materialized).
  feat_fin<<<dim3(B, 4), 256, 0, stream>>>(
      t2, t3, m2, r2, m3, r3, zcur, accbuf[flip], 1.f, dt / 6.f, featp);
  head2<<<B, 256, 0, stream>>>(featp, ow, ob, out);
}

// Round 18
// 1303.509 us; speedup vs baseline: 1.4249x; 1.4249x over previous
//
#include <hip/hip_runtime.h>
#include <hip/hip_bf16.h>
#include <cstddef>

// Problem constants
constexpr int B = 128;
constexpr int T = 500;
constexpr int C = 128;     // n_maps
constexpr int CIN = 80;    // n_mels
constexpr int NL = 35;     // labels
constexpr size_t NBCT = (size_t)B * C * T;  // 8,192,000 floats
constexpr int WPAD = 132;                   // LDS i-stride (conflict-free)
constexpr int I0 = 96;                      // conv0 padded input channels
constexpr int IPAD0 = 104;                  // conv0 LDS i-stride
constexpr int NT = 64;                      // conv t-tile
constexpr int NPART = 1024;                 // partial-stats rows

typedef __attribute__((ext_vector_type(8))) _Float16 half8;  // 8 fp16 = 4 VGPR
typedef __attribute__((ext_vector_type(4))) _Float16 half4;
typedef __attribute__((ext_vector_type(4))) float f32x4;

// Static device scratch. Activations in [b][t][c] layout.
__device__ float g_zA[NBCT];         // RK4 state ping (fp32)
__device__ float g_zB[NBCT];         // RK4 state pong (fp32)
__device__ _Float16 g_z16[NBCT];     // fp16 snapshot of current z (refreshed at fin)
__device__ _Float16 g_accA[NBCT];    // RK4 k-accumulator ping (fp16)
__device__ _Float16 g_accB[NBCT];    // RK4 k-accumulator pong (fp16)
__device__ _Float16 g_t1[NBCT];      // conv1 out (fp16, pre-BN)
__device__ _Float16 g_t2[NBCT];      // conv2 out (fp16, pre-BN)
__device__ _Float16 g_t3[NBCT];      // conv3 out (fp16, pre-BN)
// Per-block partial stats, layout [p][c] (512B-contiguous block stores).
__device__ float g_ps1[NPART * C], g_pq1[NPART * C];
__device__ float g_ps2[NPART * C], g_pq2[NPART * C];
__device__ float g_ps3[NPART * C], g_pq3[NPART * C];
__device__ float g_m1[C], g_r1[C], g_m2[C], g_r2[C], g_m3[C], g_r3[C];
__device__ float g_featp[B * 4 * C];              // head partial sums
// conv0 weights, layout [kw][o][i] (i-stride I0), fp16
__device__ _Float16 g_w0f[3 * C * I0];
// main conv weights, MFMA-native layout [kw][kseg=i>>3][o][j=i&7], fp16
__device__ _Float16 g_w1f[9 * C * C];
__device__ _Float16 g_w2f[9 * C * C];
__device__ _Float16 g_w3f[1 * C * C];

__device__ inline half8 h8zero() {
  half8 v;
#pragma unroll
  for (int j = 0; j < 8; j++) v[j] = (_Float16)0.f;
  return v;
}

__inline__ __device__ float wave_sum(float v) {
  for (int off = 32; off; off >>= 1) v += __shfl_down(v, off);
  return v;
}

// XCD-aware swizzle of the 1024-block conv grid (8 tiles x 128 b).
__device__ inline void swz_block(int& tile, int& b) {
  int flat = blockIdx.y * 8 + blockIdx.x;
  int swz = (flat & 7) * 128 + (flat >> 3);
  tile = swz & 7;
  b = swz >> 3;
}

// ---------------------------------------------------------------------------
// Weight prep: w [O][I][KW] fp32 -> fp16, layout [kw][i>>3][o][i&7]
// ---------------------------------------------------------------------------
template <int KW>
__global__ __launch_bounds__(256) void prep_weights_f16(
    const float* __restrict__ w, _Float16* __restrict__ wf) {
  int idx = blockIdx.x * 256 + threadIdx.x;
  if (idx >= C * C * KW) return;
  int kw = idx % KW;
  int i = (idx / KW) % C;
  int o = idx / (KW * C);
  size_t dst = (((size_t)kw * 16 + (i >> 3)) * C + o) * 8 + (i & 7);
  wf[dst] = (_Float16)w[idx];
}

// conv0 weights: w0 [O=128][I=80][3] -> [3][O][I0=96] fp16 (zero-padded i>=80)
__global__ __launch_bounds__(256) void prep_w0_f16(
    const float* __restrict__ w, _Float16* __restrict__ wf) {
  int idx = blockIdx.x * 256 + threadIdx.x;
  if (idx >= 3 * C * I0) return;
  int i = idx % I0;
  int o = (idx / I0) % C;
  int kw = idx / (I0 * C);
  float v = 0.f;
  if (i < CIN) v = w[((size_t)o * CIN + i) * 3 + kw];
  wf[((size_t)kw * C + o) * I0 + i] = (_Float16)v;
}

// ---------------------------------------------------------------------------
// Reduce partials -> mean, rstd per channel. Grid C blocks (one per
// channel — R17 ERRATA: 8-block grids are a latency-bound serial tail on a
// 256-CU chip, +500us total). [p][c] indexing: strided reads, L2-absorbed
// (16 channel-blocks share each 64B line; arrays are 512KB, L2-resident).
// ---------------------------------------------------------------------------
__device__ inline void reduce_one(const float* __restrict__ ps,
                                  const float* __restrict__ pq,
                                  float* __restrict__ om,
                                  float* __restrict__ orr, int c) {
  float s = 0.f, q = 0.f;
  for (int p = threadIdx.x; p < NPART; p += 256) {
    s += ps[(size_t)p * C + c];
    q += pq[(size_t)p * C + c];
  }
  s = wave_sum(s);
  q = wave_sum(q);
  __shared__ float ls[8];
  int wv = threadIdx.x >> 6, ln = threadIdx.x & 63;
  if (ln == 0) { ls[wv] = s; ls[4 + wv] = q; }
  __syncthreads();
  if (threadIdx.x == 0) {
    float S = ls[0] + ls[1] + ls[2] + ls[3];
    float Q = ls[4] + ls[5] + ls[6] + ls[7];
    const float invn = 1.f / 64000.f;
    float m = S * invn;
    float v = Q * invn - m * m;
    om[c] = m;
    orr[c] = rsqrtf(v + 1e-5f);
  }
}

__global__ __launch_bounds__(256) void reduce_stats(
    const float* __restrict__ ps, const float* __restrict__ pq,
    float* __restrict__ om, float* __restrict__ orr) {
  reduce_one(ps, pq, om, orr, blockIdx.x);
}

__global__ __launch_bounds__(256) void reduce_stats2(
    const float* __restrict__ psA, const float* __restrict__ pqA,
    float* __restrict__ omA, float* __restrict__ orA,
    const float* __restrict__ psB, const float* __restrict__ pqB,
    float* __restrict__ omB, float* __restrict__ orB) {
  if (blockIdx.y == 0)
    reduce_one(psA, pqA, omA, orA, blockIdx.x);
  else
    reduce_one(psB, pqB, omB, orB, blockIdx.x);
}

// ---------------------------------------------------------------------------
// Epilogues (direct fragment stores — LDS-transpose epilogue measured
// byte-neutral in R16). D layout (16x16x32): col(t)=lane&15, row(o)=quad*4+reg.
// ---------------------------------------------------------------------------
template <int NG, int NTG>
__device__ inline void store_and_stats_f(f32x4 (&dacc)[NG][NTG],
                                         float* __restrict__ outb,
                                         float* __restrict__ ssum,
                                         float* __restrict__ ssq, int tbase,
                                         int og0, int quad, int m15) {
#pragma unroll
  for (int g = 0; g < NG; g++) {
    float rs[4] = {0.f, 0.f, 0.f, 0.f}, rq[4] = {0.f, 0.f, 0.f, 0.f};
#pragma unroll
    for (int tg = 0; tg < NTG; tg++) {
      int t = tbase + tg * 16 + m15;
      bool valid = t < T;
      f32x4 d = dacc[g][tg];
      if (valid)
        *(f32x4*)(outb + (size_t)t * C + (og0 + g) * 16 + quad * 4) = d;
#pragma unroll
      for (int r = 0; r < 4; r++) {
        float v = valid ? d[r] : 0.f;
        rs[r] += v;
        rq[r] += v * v;
      }
    }
#pragma unroll
    for (int sh = 1; sh < 16; sh <<= 1) {
#pragma unroll
      for (int r = 0; r < 4; r++) {
        rs[r] += __shfl_xor(rs[r], sh);
        rq[r] += __shfl_xor(rq[r], sh);
      }
    }
    if (m15 == 0) {
      int o = (og0 + g) * 16 + quad * 4;
#pragma unroll
      for (int r = 0; r < 4; r++) {
        atomicAdd(&ssum[o + r], rs[r]);
        atomicAdd(&ssq[o + r], rq[r]);
      }
    }
  }
}

template <int NG, int NTG>
__device__ inline void store_and_stats_h(f32x4 (&dacc)[NG][NTG],
                                         _Float16* __restrict__ outb,
                                         float* __restrict__ ssum,
                                         float* __restrict__ ssq, int tbase,
                                         int og0, int quad, int m15) {
#pragma unroll
  for (int g = 0; g < NG; g++) {
    float rs[4] = {0.f, 0.f, 0.f, 0.f}, rq[4] = {0.f, 0.f, 0.f, 0.f};
#pragma unroll
    for (int tg = 0; tg < NTG; tg++) {
      int t = tbase + tg * 16 + m15;
      bool valid = t < T;
      f32x4 d = dacc[g][tg];
      if (valid) {
        half4 h;
#pragma unroll
        for (int r = 0; r < 4; r++) h[r] = (_Float16)d[r];
        *(half4*)(outb + (size_t)t * C + (og0 + g) * 16 + quad * 4) = h;
      }
#pragma unroll
      for (int r = 0; r < 4; r++) {
        float v = valid ? d[r] : 0.f;
        rs[r] += v;
        rq[r] += v * v;
      }
    }
#pragma unroll
    for (int sh = 1; sh < 16; sh <<= 1) {
#pragma unroll
      for (int r = 0; r < 4; r++) {
        rs[r] += __shfl_xor(rs[r], sh);
        rq[r] += __shfl_xor(rq[r], sh);
      }
    }
    if (m15 == 0) {
      int o = (og0 + g) * 16 + quad * 4;
#pragma unroll
      for (int r = 0; r < 4; r++) {
        atomicAdd(&ssum[o + r], rs[r]);
        atomicAdd(&ssq[o + r], rq[r]);
      }
    }
  }
}

// ---------------------------------------------------------------------------
// conv13f: fused combine(i-1) + conv1 (KW=9) + conv3 (KW=1). R17 structure
// unchanged (measured 49.2us): 256 thr, og0=wv*2, NTG=4, z16 snapshot,
// XCD swizzle, ping-pong buffers, [p][c] stats stores.
// ---------------------------------------------------------------------------
__global__ __launch_bounds__(256, 4) void conv13f(
    const _Float16* __restrict__ t2g, const _Float16* __restrict__ t3g,
    const float* __restrict__ m2, const float* __restrict__ r2,
    const float* __restrict__ m3, const float* __restrict__ r3,
    const float* __restrict__ zc, _Float16* __restrict__ z16,
    const _Float16* __restrict__ accr, float* __restrict__ zn,
    _Float16* __restrict__ accw, const _Float16* __restrict__ w9,
    const _Float16* __restrict__ w1, _Float16* __restrict__ out1,
    _Float16* __restrict__ out3, float* __restrict__ ps1,
    float* __restrict__ pq1, float* __restrict__ ps3,
    float* __restrict__ pq3, float wacc, float anext, int mode, int initf,
    int finf) {
  constexpr int PAD = 4;
  constexpr int ROWS = NT + 8;  // 72
  __shared__ __align__(16) _Float16 sh[ROWS * WPAD];
  __shared__ float ssum1[C], ssq1[C], ssum3[C], ssq3[C];
  __shared__ float sm2[C], sr2[C], sm3[C], sr3[C];

  const int tid = threadIdx.x;
  int tile, b;
  swz_block(tile, b);
  const int t0 = tile * NT;

  if (tid < 128) {
    ssum1[tid] = 0.f; ssq1[tid] = 0.f;
    ssum3[tid] = 0.f; ssq3[tid] = 0.f;
    if (mode) {
      sm2[tid] = m2[tid]; sr2[tid] = r2[tid];
      sm3[tid] = m3[tid]; sr3[tid] = r3[tid];
    }
  }
  __syncthreads();  // BN params ready before staging uses them

  for (int e = tid; e < ROWS * 16; e += 256) {
    int r = e >> 4;
    int c8 = e & 15;
    int t = t0 - PAD + r;
    half8 v = h8zero();
    if (t >= 0 && t < T) {
      size_t off = (size_t)b * T * C + (size_t)t * C + c8 * 8;
      if (mode == 0) {
        v = *(const half8*)(z16 + off);
      } else {
        half8 h2 = *(const half8*)(t2g + off);
        half8 h3 = *(const half8*)(t3g + off);
        float zf[8];
        if (finf) {
          float4 z0 = *(const float4*)(zc + off);
          float4 z1 = *(const float4*)(zc + off + 4);
          zf[0] = z0.x; zf[1] = z0.y; zf[2] = z0.z; zf[3] = z0.w;
          zf[4] = z1.x; zf[5] = z1.y; zf[6] = z1.z; zf[7] = z1.w;
        } else {
          half8 hz = *(const half8*)(z16 + off);
#pragma unroll
          for (int j = 0; j < 8; j++) zf[j] = (float)hz[j];
        }
        half8 ha = h8zero();
        if (!initf) ha = *(const half8*)(accr + off);
        int c = c8 * 8;
        float va[8], zo[8];
#pragma unroll
        for (int j = 0; j < 8; j++) {
          float f2 = (float)h2[j];
          float f3 = (float)h3[j];
          float k = fmaxf((f2 - sm2[c + j]) * sr2[c + j] +
                              fmaxf((f3 - sm3[c + j]) * sr3[c + j], 0.f),
                          0.f);
          va[j] = initf ? wacc * k : (float)ha[j] + wacc * k;
          zo[j] = zf[j] + anext * (finf ? va[j] : k);
          v[j] = (_Float16)zo[j];
        }
        bool owned = (r >= PAD) && (r < PAD + NT);
        if (owned) {
          if (finf) {
            *(float4*)(zn + off) = make_float4(zo[0], zo[1], zo[2], zo[3]);
            *(float4*)(zn + off + 4) = make_float4(zo[4], zo[5], zo[6], zo[7]);
            *(half8*)(z16 + off) = v;  // refresh fp16 snapshot of new z
          } else {
            half8 aw;
#pragma unroll
            for (int j = 0; j < 8; j++) aw[j] = (_Float16)va[j];
            *(half8*)(accw + off) = aw;
          }
        }
      }
    }
    *(half8*)&sh[r * WPAD + c8 * 8] = v;
  }
  __syncthreads();

  const int wv = tid >> 6;
  const int lane = tid & 63;
  const int quad = lane >> 4;
  const int m15 = lane & 15;
  const int og0 = wv * 2;  // waves own disjoint o-pairs: no A duplication

  const half8* __restrict__ A9 = (const half8*)w9;
  const half8* __restrict__ A1 = (const half8*)w1;

  // --- conv3 (KW=1): 4 rounds, retire accumulator early ---
  {
    f32x4 d3[2][4];
#pragma unroll
    for (int g = 0; g < 2; g++)
#pragma unroll
      for (int tg = 0; tg < 4; tg++) d3[g][tg] = f32x4{0.f, 0.f, 0.f, 0.f};
#pragma unroll
    for (int ic = 0; ic < 4; ic++) {
      const int kof = ic * 32 + quad * 8;
      half8 af[2];
#pragma unroll
      for (int g = 0; g < 2; g++)
        af[g] = A1[(ic * 4 + quad) * C + (og0 + g) * 16 + m15];
      half8 bf[4];
#pragma unroll
      for (int tg = 0; tg < 4; tg++)
        bf[tg] = *(const half8*)(sh + (tg * 16 + m15 + PAD) * WPAD + kof);
#pragma unroll
      for (int g = 0; g < 2; g++)
#pragma unroll
        for (int tg = 0; tg < 4; tg++)
          d3[g][tg] = __builtin_amdgcn_mfma_f32_16x16x32_f16(
              af[g], bf[tg], d3[g][tg], 0, 0, 0);
    }
    _Float16* __restrict__ o3b = out3 + (size_t)b * T * C;
    store_and_stats_h<2, 4>(d3, o3b, ssum3, ssq3, t0, og0, quad, m15);
  }

  // --- conv1 (KW=9): 36 rounds ---
  f32x4 d1[2][4];
#pragma unroll
  for (int g = 0; g < 2; g++)
#pragma unroll
    for (int tg = 0; tg < 4; tg++) d1[g][tg] = f32x4{0.f, 0.f, 0.f, 0.f};

  for (int kw = 0; kw < 9; kw++) {
#pragma unroll
    for (int ic = 0; ic < 4; ic++) {
      const int kof = ic * 32 + quad * 8;
      half8 af[2];
#pragma unroll
      for (int g = 0; g < 2; g++)
        af[g] = A9[(kw * 16 + ic * 4 + quad) * C + (og0 + g) * 16 + m15];
      half8 bf[4];
#pragma unroll
      for (int tg = 0; tg < 4; tg++)
        bf[tg] = *(const half8*)(sh + (tg * 16 + m15 + kw) * WPAD + kof);
#pragma unroll
      for (int g = 0; g < 2; g++)
#pragma unroll
        for (int tg = 0; tg < 4; tg++)
          d1[g][tg] = __builtin_amdgcn_mfma_f32_16x16x32_f16(
              af[g], bf[tg], d1[g][tg], 0, 0, 0);
    }
  }

  _Float16* __restrict__ o1b = out1 + (size_t)b * T * C;
  store_and_stats_h<2, 4>(d1, o1b, ssum1, ssq1, t0, og0, quad, m15);
  __syncthreads();
  int p = b * 8 + tile;
  if (tid < 128) {
    ps1[(size_t)p * C + tid] = ssum1[tid];
    pq1[(size_t)p * C + tid] = ssq1[tid];
    ps3[(size_t)p * C + tid] = ssum3[tid];
    pq3[(size_t)p * C + tid] = ssq3[tid];
  }
}

// ---------------------------------------------------------------------------
// conv2 (KW=9, PAD=4): BN+relu on staging from precomputed mean/rstd;
// minimal-A geometry + XCD swizzle; [p][c] stats store.
// ---------------------------------------------------------------------------
__global__ __launch_bounds__(256, 4) void conv2_bn(
    const _Float16* __restrict__ in, const _Float16* __restrict__ wf,
    const float* __restrict__ bnm, const float* __restrict__ bnr,
    _Float16* __restrict__ out, float* __restrict__ ps,
    float* __restrict__ pq) {
  constexpr int KW = 9, PAD = 4;
  constexpr int ROWS = NT + KW - 1;  // 72
  __shared__ __align__(16) _Float16 sh[ROWS * WPAD];
  __shared__ float ssum[C], ssq[C];
  __shared__ float sbm[C], sbr[C];

  const int tid = threadIdx.x;
  int tile, b;
  swz_block(tile, b);
  const int t0 = tile * NT;

  if (tid < 128) {
    sbm[tid] = bnm[tid];
    sbr[tid] = bnr[tid];
    ssum[tid] = 0.f;
    ssq[tid] = 0.f;
  }
  __syncthreads();  // BN params ready before staging uses them

  const _Float16* __restrict__ inb = in + (size_t)b * T * C;
  for (int e = tid; e < ROWS * 16; e += 256) {
    int r = e >> 4;
    int c8 = e & 15;
    int t = t0 - PAD + r;
    half8 v = h8zero();
    if (t >= 0 && t < T) {
      half8 u = *(const half8*)(inb + (size_t)t * C + c8 * 8);
      int c = c8 * 8;
#pragma unroll
      for (int j = 0; j < 8; j++) {
        float f = (float)u[j];
        f = fmaxf((f - sbm[c + j]) * sbr[c + j], 0.f);
        v[j] = (_Float16)f;
      }
    }
    *(half8*)&sh[r * WPAD + c8 * 8] = v;
  }
  __syncthreads();

  const int wv = tid >> 6;
  const int lane = tid & 63;
  const int quad = lane >> 4;
  const int m15 = lane & 15;
  const int og0 = wv * 2;

  const half8* __restrict__ Af = (const half8*)wf;

  f32x4 dacc[2][4];
#pragma unroll
  for (int g = 0; g < 2; g++)
#pragma unroll
    for (int tg = 0; tg < 4; tg++) dacc[g][tg] = f32x4{0.f, 0.f, 0.f, 0.f};

  for (int kw = 0; kw < 9; kw++) {
#pragma unroll
    for (int ic = 0; ic < 4; ic++) {
      const int kof = ic * 32 + quad * 8;
      half8 af[2];
#pragma unroll
      for (int g = 0; g < 2; g++)
        af[g] = Af[(kw * 16 + ic * 4 + quad) * C + (og0 + g) * 16 + m15];
      half8 bf[4];
#pragma unroll
      for (int tg = 0; tg < 4; tg++)
        bf[tg] = *(const half8*)(sh + (tg * 16 + m15 + kw) * WPAD + kof);
#pragma unroll
      for (int g = 0; g < 2; g++)
#pragma unroll
        for (int tg = 0; tg < 4; tg++)
          dacc[g][tg] = __builtin_amdgcn_mfma_f32_16x16x32_f16(
              af[g], bf[tg], dacc[g][tg], 0, 0, 0);
    }
  }

  _Float16* __restrict__ outb = out + (size_t)b * T * C;
  store_and_stats_h<2, 4>(dacc, outb, ssum, ssq, t0, og0, quad, m15);
  __syncthreads();
  int p = b * 8 + tile;
  if (tid < 128) {
    ps[(size_t)p * C + tid] = ssum[tid];
    pq[(size_t)p * C + tid] = ssq[tid];
  }
}

// ---------------------------------------------------------------------------
// conv0: single fp16 16x16x32 MFMA. Output z fp32; [p][c] stats store.
// ---------------------------------------------------------------------------
__global__ __launch_bounds__(256) void conv0_mfma(
    const float* __restrict__ in, const _Float16* __restrict__ wf,
    float* __restrict__ out, float* __restrict__ ps, float* __restrict__ pq) {
  constexpr int KW = 3, PAD = 1;
  constexpr int ROWS = NT + KW - 1;  // 66
  __shared__ __align__(16) _Float16 sh[ROWS * IPAD0];
  __shared__ float ssum[C], ssq[C];

  const int tid = threadIdx.x;
  const int tile = blockIdx.x;
  const int b = blockIdx.y;
  const int t0 = tile * NT;

  if (tid < 128) { ssum[tid] = 0.f; ssq[tid] = 0.f; }
  __syncthreads();

  const float* __restrict__ inb = in + (size_t)b * CIN * T;
  for (int e = tid; e < I0 * ROWS; e += 256) {
    int i = e / ROWS;
    int r = e % ROWS;
    int t = t0 - PAD + r;
    float v = 0.f;
    if (i < CIN && t >= 0 && t < T) v = inb[(size_t)i * T + t];
    sh[r * IPAD0 + i] = (_Float16)v;
  }
  __syncthreads();

  const int wv = tid >> 6;
  const int lane = tid & 63;
  const int quad = lane >> 4;
  const int m15 = lane & 15;
  const int og0 = wv * 2;

  f32x4 dacc[2][4];
#pragma unroll
  for (int g = 0; g < 2; g++)
#pragma unroll
    for (int tg = 0; tg < 4; tg++) dacc[g][tg] = f32x4{0.f, 0.f, 0.f, 0.f};

  for (int kw = 0; kw < KW; kw++) {
    const _Float16* __restrict__ wk = wf + (size_t)kw * C * I0;
#pragma unroll
    for (int ic = 0; ic < 3; ic++) {
      const int kof = ic * 32 + quad * 8;
      half8 af[2];
#pragma unroll
      for (int g = 0; g < 2; g++) {
        size_t off = (size_t)((og0 + g) * 16 + m15) * I0 + kof;
        af[g] = *(const half8*)(wk + off);
      }
      half8 bf[4];
#pragma unroll
      for (int tg = 0; tg < 4; tg++) {
        int off = (tg * 16 + m15 + kw) * IPAD0 + kof;
        bf[tg] = *(const half8*)(sh + off);
      }
#pragma unroll
      for (int g = 0; g < 2; g++)
#pragma unroll
        for (int tg = 0; tg < 4; tg++)
          dacc[g][tg] = __builtin_amdgcn_mfma_f32_16x16x32_f16(
              af[g], bf[tg], dacc[g][tg], 0, 0, 0);
    }
  }

  float* __restrict__ outb = out + (size_t)b * T * C;
  store_and_stats_f<2, 4>(dacc, outb, ssum, ssq, t0, og0, quad, m15);
  __syncthreads();
  int p = b * 8 + tile;
  if (tid < 128) {
    ps[(size_t)p * C + tid] = ssum[tid];
    pq[(size_t)p * C + tid] = ssq[tid];
  }
}

// ---------------------------------------------------------------------------
// z = relu((z - m[c]) * r[c]) in place (fp32) + fp16 snapshot z16.
// ---------------------------------------------------------------------------
__global__ __launch_bounds__(256) void apply_bn_relu(
    float* __restrict__ x, const float* __restrict__ m,
    const float* __restrict__ r, _Float16* __restrict__ zh) {
  __shared__ float sm[C], sr[C];
  if (threadIdx.x < 128) {
    sm[threadIdx.x] = m[threadIdx.x];
    sr[threadIdx.x] = r[threadIdx.x];
  }
  __syncthreads();
  const size_t total4 = NBCT / 4;
  size_t stride = (size_t)gridDim.x * 256;
  for (size_t i4 = (size_t)blockIdx.x * 256 + threadIdx.x; i4 < total4;
       i4 += stride) {
    int c = (int)((i4 & 31) * 4);
    float4 v = ((float4*)x)[i4];
    v.x = fmaxf((v.x - sm[c]) * sr[c], 0.f);
    v.y = fmaxf((v.y - sm[c + 1]) * sr[c + 1], 0.f);
    v.z = fmaxf((v.z - sm[c + 2]) * sr[c + 2], 0.f);
    v.w = fmaxf((v.w - sm[c + 3]) * sr[c + 3], 0.f);
    ((float4*)x)[i4] = v;
    half4 h;
    h[0] = (_Float16)v.x;
    h[1] = (_Float16)v.y;
    h[2] = (_Float16)v.z;
    h[3] = (_Float16)v.w;
    *(half4*)(zh + i4 * 4) = h;
  }
}

// ---------------------------------------------------------------------------
// feat_fin: fused final combine + pooling. z_final = z + anext*(acc+wacc*k)
// computed on the fly (never materialized); partial t-sums into featp.
// grid (B, 4), 256 thr (2 t-phases x 128 channels).
// ---------------------------------------------------------------------------
__global__ __launch_bounds__(256) void feat_fin(
    const _Float16* __restrict__ t2, const _Float16* __restrict__ t3,
    const float* __restrict__ m2, const float* __restrict__ r2,
    const float* __restrict__ m3, const float* __restrict__ r3,
    const float* __restrict__ z, const _Float16* __restrict__ acc,
    float wacc, float anext, float* __restrict__ fp) {
  __shared__ float sm2[C], sr2[C], sm3[C], sr3[C];
  if (threadIdx.x < 128) {
    sm2[threadIdx.x] = m2[threadIdx.x];
    sr2[threadIdx.x] = r2[threadIdx.x];
    sm3[threadIdx.x] = m3[threadIdx.x];
    sr3[threadIdx.x] = r3[threadIdx.x];
  }
  __syncthreads();
  const int b = blockIdx.x;
  const int s = blockIdx.y;
  const int c = threadIdx.x & 127;
  const int h = threadIdx.x >> 7;
  float sum = 0.f;
  for (int t = s * 125 + h; t < (s + 1) * 125; t += 2) {
    size_t off = (size_t)b * T * C + (size_t)t * C + c;
    float f2 = (float)t2[off];
    float f3 = (float)t3[off];
    float k = fmaxf((f2 - sm2[c]) * sr2[c] +
                        fmaxf((f3 - sm3[c]) * sr3[c], 0.f),
                    0.f);
    float va = (float)acc[off] + wacc * k;
    sum += z[off] + anext * va;
  }
  __shared__ float sf[2][C];
  sf[h][c] = sum;
  __syncthreads();
  if (threadIdx.x < 128)
    fp[((size_t)b * 4 + s) * C + threadIdx.x] =
        sf[0][threadIdx.x] + sf[1][threadIdx.x];
}

// head, phase 2: feat = sum(partials)/500; out = feat @ ow^T + ob.
__global__ __launch_bounds__(256) void head2(
    const float* __restrict__ fp, const float* __restrict__ ow,
    const float* __restrict__ ob, float* __restrict__ out) {
  const int b = blockIdx.x;
  __shared__ float feat[C];
  if (threadIdx.x < 128) {
    float s = 0.f;
#pragma unroll
    for (int p = 0; p < 4; p++) s += fp[((size_t)b * 4 + p) * C + threadIdx.x];
    feat[threadIdx.x] = s * (1.f / 500.f);
  }
  __syncthreads();
  if (threadIdx.x < NL) {
    int l = threadIdx.x;
    float o = ob[l];
    for (int j = 0; j < C; j++) o = fmaf(feat[j], ow[l * C + j], o);
    out[b * NL + l] = o;
  }
}

// ---------------------------------------------------------------------------
extern "C" void kernel_launch(void* const* d_in, const int* in_sizes, int n_in,
                              void* d_out, int out_size, void* d_ws,
                              size_t ws_size, hipStream_t stream) {
  const float* x  = (const float*)d_in[0];
  const float* w0 = (const float*)d_in[1];
  const float* w1 = (const float*)d_in[2];
  const float* w2 = (const float*)d_in[3];
  const float* w3 = (const float*)d_in[4];
  const float* ow = (const float*)d_in[5];
  const float* ob = (const float*)d_in[6];
  float* out = (float*)d_out;

  static float *zA, *zB, *featp;
  static float *ps1, *pq1, *ps2, *pq2, *ps3, *pq3;
  static float *m1, *r1, *m2, *r2, *m3, *r3;
  static _Float16 *z16, *accA, *accB, *t1, *t2, *t3;
  static _Float16 *w0f, *w1f, *w2f, *w3f;
  static bool inited = false;
  if (!inited) {
    void* p;
#define GET(sym, var) hipGetSymbolAddress(&p, HIP_SYMBOL(sym)); var = (decltype(var))p;
    GET(g_zA, zA) GET(g_zB, zB) GET(g_z16, z16)
    GET(g_accA, accA) GET(g_accB, accB)
    GET(g_t1, t1) GET(g_t2, t2) GET(g_t3, t3)
    GET(g_ps1, ps1) GET(g_pq1, pq1) GET(g_ps2, ps2) GET(g_pq2, pq2)
    GET(g_ps3, ps3) GET(g_pq3, pq3)
    GET(g_m1, m1) GET(g_r1, r1) GET(g_m2, m2) GET(g_r2, r2)
    GET(g_m3, m3) GET(g_r3, r3) GET(g_featp, featp)
    GET(g_w0f, w0f) GET(g_w1f, w1f) GET(g_w2f, w2f) GET(g_w3f, w3f)
#undef GET
    inited = true;
  }

  // Weight prep (cheap, every launch)
  prep_w0_f16<<<(3 * C * I0 + 255) / 256, 256, 0, stream>>>(w0, w0f);
  prep_weights_f16<9><<<(C * C * 9 + 255) / 256, 256, 0, stream>>>(w1, w1f);
  prep_weights_f16<9><<<(C * C * 9 + 255) / 256, 256, 0, stream>>>(w2, w2f);
  prep_weights_f16<1><<<(C * C * 1 + 255) / 256, 256, 0, stream>>>(w3, w3f);

  const dim3 convGrid(8, B);   // NT=64 tiles -> 1024 blocks of 256 thr
  const int ewGrid = 1024;
  const float dt = 0.25f;

  // conv0 -> reduce -> bn+relu (into zA fp32 + z16 fp16).
  conv0_mfma<<<dim3(8, B), 256, 0, stream>>>(x, w0f, zA, ps1, pq1);
  reduce_stats<<<C, 256, 0, stream>>>(ps1, pq1, m1, r1);
  apply_bn_relu<<<ewGrid, 256, 0, stream>>>(zA, m1, r1, z16);

  const float waccs[4] = {1.f, 2.f, 2.f, 1.f};
  const float anexts[4] = {0.5f * dt, 0.5f * dt, dt, dt / 6.f};

  float* zcur = zA;
  float* znext = zB;
  _Float16* accbuf[2] = {accA, accB};
  int flip = 0;

  for (int i = 0; i < 16; i++) {
    int sp = (i + 3) % 4;  // previous iteration's s (valid for i>=1)
    int mode = (i == 0) ? 0 : 1;
    int initf = (sp == 0) ? 1 : 0;
    int finf = (sp == 3) ? 1 : 0;
    conv13f<<<convGrid, 256, 0, stream>>>(
        t2, t3, m2, r2, m3, r3, zcur, z16, accbuf[flip], znext,
        accbuf[flip ^ 1], w1f, w3f, t1, t3, ps1, pq1, ps3, pq3,
        mode ? waccs[sp] : 0.f, mode ? anexts[sp] : 0.f, mode, initf, finf);
    if (i >= 1) {
      if (!finf) {
        flip ^= 1;                       // acc written into flip^1
      } else {
        float* tmp = zcur; zcur = znext; znext = tmp;  // fin wrote z
      }
    }
    reduce_stats2<<<dim3(C, 2), 256, 0, stream>>>(
        ps1, pq1, m1, r1, ps3, pq3, m3, r3);
    conv2_bn<<<convGrid, 256, 0, stream>>>(
        t1, w2f, m1, r1, t2, ps2, pq2);
    reduce_stats<<<C, 256, 0, stream>>>(ps2, pq2, m2, r2);
  }

  // Fused final combine + pooling (z_final never materialized).
  feat_fin<<<dim3(B, 4), 256, 0, stream>>>(
      t2, t3, m2, r2, m3, r3, zcur, accbuf[flip], 1.f, dt / 6.f, featp);
  head2<<<B, 256, 0, stream>>>(featp, ow, ob, out);
}